// Round 7
// baseline (239.263 us; speedup 1.0000x reference)
//
#include <hip/hip_runtime.h>
#include <stdint.h>

#define NROWS 8192
#define KDIM  512
#define BM    128
#define NT    (NROWS / BM)                  // 64 tiles per dim
#define NKT   (KDIM / 32)                   // 16 k-steps of 32

typedef __attribute__((ext_vector_type(8))) short bf16x8;
typedef __attribute__((ext_vector_type(4))) float f32x4;

__device__ __forceinline__ unsigned short f32_to_bf16(float f) {
  union { float f; unsigned int u; } v; v.f = f;
  unsigned int u = v.u;
  u += 0x7FFFu + ((u >> 16) & 1u);   // round-to-nearest-even
  return (unsigned short)(u >> 16);
}

// Kernel 1: row-normalize fp32 -> bf16 (RNE), plain row-major layout
// (R6 removed LDS staging, so no swizzle needed).
__global__ __launch_bounds__(128) void prep_kernel(
    const float* __restrict__ src, unsigned short* __restrict__ dst,
    float* __restrict__ acc) {
  const int row = blockIdx.x;
  const int tid = threadIdx.x;
  const float4 v = ((const float4*)src)[row * 128 + tid];
  float ss = v.x * v.x + v.y * v.y + v.z * v.z + v.w * v.w;
  #pragma unroll
  for (int off = 32; off > 0; off >>= 1) ss += __shfl_down(ss, off);
  __shared__ float red[2];
  __shared__ float s_rn;
  const int lane = tid & 63, w = tid >> 6;
  if (lane == 0) red[w] = ss;
  __syncthreads();
  if (tid == 0) {
    s_rn = 1.0f / sqrtf(red[0] + red[1]);   // norms ~22.6, EPS can never fire
    if (row == 0) *acc = 0.0f;
  }
  __syncthreads();
  const float rn = s_rn;
  ushort4 o;
  o.x = f32_to_bf16(v.x * rn);
  o.y = f32_to_bf16(v.y * rn);
  o.z = f32_to_bf16(v.z * rn);
  o.w = f32_to_bf16(v.w * rn);
  ((ushort4*)dst)[row * 128 + tid] = o;
}

// Kernel 2: bf16 MFMA GEMM (idn @ idn^T) fused with clamp, diagonal masking,
// and full reduction -- NO LDS in the dataflow (R6). Each lane loads its MFMA
// A/B fragments directly from global (16 B dwordx4, 16 lines/wave-instr,
// line-coalesced), register ping-pong one K-step ahead. Zero barriers.
// R0-R5 post-mortems: every LDS-staged variant (any barrier/waitcnt/buffer
// scheme) pinned at 67-80 us with all pipes <31% utilized -- the
// global_load_lds->ds_read chain itself was the serializer.
// 2D grid: linear id = bi*64+bj, 64%8==0 => XCD = bj%8 -> per-XCD B-set
// (~1 MB) stays L2-resident (R1 A/B: 31 MB vs 74 MB fetch). Upper-tri blocks
// only; strictly-upper tiles weighted 2x by symmetry.
__global__ __launch_bounds__(256, 3) void sim_reduce_kernel(
    const unsigned short* __restrict__ idn, float* __restrict__ acc) {
  const int bi = blockIdx.y;
  const int bj = blockIdx.x;
  if (bj < bi) return;               // block-uniform early exit (dead block)

  __shared__ float red[4];

  const int tid  = threadIdx.x;      // 0..255, 4 waves
  const int lane = tid & 63;
  const int w    = tid >> 6;
  const int wr   = (w >> 1) * 64;    // wave's 64x64 quadrant
  const int wc   = (w & 1) * 64;
  const int q    = lane >> 4;        // k-chunk (0..3) this lane holds
  const int r16  = lane & 15;        // row-within-16 this lane holds

  // Per-lane fragment base pointers, one per 16-row slice (16 KB apart --
  // too far for the 13-bit immediate, so 4 bases each; k-step offset
  // t*64 B rides in the immediate).
  const unsigned short* pA[4];
  const unsigned short* pB[4];
  #pragma unroll
  for (int i = 0; i < 4; i++) {
    pA[i] = idn + (size_t)(bi * BM + wr + i * 16 + r16) * KDIM + q * 8;
    pB[i] = idn + (size_t)(bj * BM + wc + i * 16 + r16) * KDIM + q * 8;
  }

  f32x4 acc_f[4][4];
  #pragma unroll
  for (int i = 0; i < 4; i++)
    #pragma unroll
    for (int j = 0; j < 4; j++)
      acc_f[i][j] = (f32x4){0.f, 0.f, 0.f, 0.f};

  // Register ping-pong: stage t+1's 8 fragments while MFMAing tile t.
  bf16x8 a[2][4], b[2][4];
  #pragma unroll
  for (int i = 0; i < 4; i++) {
    a[0][i] = *(const bf16x8*)(pA[i]);
    b[0][i] = *(const bf16x8*)(pB[i]);
  }

  #pragma unroll
  for (int t = 0; t < NKT; ++t) {
    const int cur = t & 1, nxt = cur ^ 1;
    if (t + 1 < NKT) {
      const int ko = (t + 1) * 32;   // shorts; byte offset (t+1)*64 <= 960
      #pragma unroll
      for (int i = 0; i < 4; i++) {
        a[nxt][i] = *(const bf16x8*)(pA[i] + ko);
        b[nxt][i] = *(const bf16x8*)(pB[i] + ko);
      }
    }
    #pragma unroll
    for (int mi = 0; mi < 4; mi++)
      #pragma unroll
      for (int ni = 0; ni < 4; ni++)
        acc_f[mi][ni] = __builtin_amdgcn_mfma_f32_16x16x32_bf16(
            a[cur][mi], b[cur][ni], acc_f[mi][ni], 0, 0, 0);
  }

  // Epilogue: clamp at zero, mask diagonal, reduce.
  // C/D layout (verified m89/m91): col = lane&15, row = (lane>>4)*4 + reg.
  float local = 0.f;
  const bool diag = (bi == bj);
  #pragma unroll
  for (int mi = 0; mi < 4; mi++)
    #pragma unroll
    for (int ni = 0; ni < 4; ni++)
      #pragma unroll
      for (int rr = 0; rr < 4; rr++) {
        const int ri = wr + mi * 16 + q * 4 + rr;
        const int ci = wc + ni * 16 + r16;
        float v = fmaxf(acc_f[mi][ni][rr], 0.f);
        if (diag && ri == ci) v = 0.f;
        local += v;
      }

  #pragma unroll
  for (int off = 32; off > 0; off >>= 1) local += __shfl_down(local, off);
  if (lane == 0) red[w] = local;
  __syncthreads();
  if (tid == 0) {
    float s = red[0] + red[1] + red[2] + red[3];
    if (!diag) s *= 2.f;             // strictly-upper tiles cover both triangles
    atomicAdd(acc, s);
  }
}

// Kernel 3: scale and write both outputs (total_loss == l_id_div, DIV_COEF=1).
__global__ void finalize_kernel(const float* __restrict__ acc, float* __restrict__ out) {
  const float m = *acc * (1.0f / ((float)NROWS * (float)NROWS));
  out[0] = m;
  out[1] = m;
}

extern "C" void kernel_launch(void* const* d_in, const int* in_sizes, int n_in,
                              void* d_out, int out_size, void* d_ws, size_t ws_size,
                              hipStream_t stream) {
  const float* id = (const float*)d_in[0];
  float* out = (float*)d_out;
  unsigned short* idn = (unsigned short*)d_ws;                     // 8 MB bf16
  float* acc = (float*)((char*)d_ws + (size_t)NROWS * KDIM * 2);

  prep_kernel<<<NROWS, 128, 0, stream>>>(id, idn, acc);
  dim3 grid(NT, NT);
  sim_reduce_kernel<<<grid, 256, 0, stream>>>(idn, acc);
  finalize_kernel<<<1, 1, 0, stream>>>(acc, out);
}

// Round 8
// 121.975 us; speedup vs baseline: 1.9616x; 1.9616x over previous
//
#include <hip/hip_runtime.h>
#include <stdint.h>

#define NROWS 8192
#define KDIM  512                           // k elems (= bytes in fp8) per row
#define BM    128
#define BK    64                            // k-bytes staged per tile
#define NT    (NROWS / BM)                  // 64 tiles per dim
#define NKT   (KDIM / BK)                   // 8 k-iters

typedef __attribute__((ext_vector_type(4))) float f32x4;
typedef long i64;

__device__ __forceinline__ void async_copy16(const unsigned char* g, unsigned char* l) {
  __builtin_amdgcn_global_load_lds(
      (const __attribute__((address_space(1))) unsigned int*)g,
      (__attribute__((address_space(3))) unsigned int*)l,
      16, 0, 0);
}

// Kernel 1: row-normalize fp32 -> fp8 e4m3 (RNE via v_cvt_pk_fp8_f32),
// PRE-SWIZZLED layout: within each row, the 16B chunk holding global k-chunk
// g sits at position g ^ (row&3) (permutation inside aligned 64B windows).
// Sim kernel then stages with lane-linear (coalesced) reads while LDS
// ds_read_b64 fragment reads land on the minimal 4-wrap bank pattern.
__global__ __launch_bounds__(128) void prep_kernel(
    const float* __restrict__ src, unsigned char* __restrict__ dst,
    float* __restrict__ acc) {
  const int row = blockIdx.x;
  const int tid = threadIdx.x;             // 128 thr x 4 elems
  const float4 v = ((const float4*)src)[row * 128 + tid];
  float ss = v.x * v.x + v.y * v.y + v.z * v.z + v.w * v.w;
  #pragma unroll
  for (int off = 32; off > 0; off >>= 1) ss += __shfl_down(ss, off);
  __shared__ float red[2];
  __shared__ float s_rn;
  const int lane = tid & 63, w = tid >> 6;
  if (lane == 0) red[w] = ss;
  __syncthreads();
  if (tid == 0) {
    s_rn = 1.0f / sqrtf(red[0] + red[1]);  // norms ~22.6, EPS can never fire
    if (row == 0) *acc = 0.0f;
  }
  __syncthreads();
  const float rn = s_rn;
  int pk = __builtin_amdgcn_cvt_pk_fp8_f32(v.x * rn, v.y * rn, 0, false);
  pk     = __builtin_amdgcn_cvt_pk_fp8_f32(v.z * rn, v.w * rn, pk, true);
  // this thread's 4 bytes live in 16B chunk cg = tid>>2 at offset (tid&3)*4;
  // whole chunk relocates to swizzled position p.
  const int cg = tid >> 2;
  const int p  = cg ^ (row & 3);
  ((unsigned int*)dst)[(row * KDIM + p * 16 + (tid & 3) * 4) >> 2] = (unsigned int)pk;
}

// Kernel 2: fp8 MFMA GEMM (idn @ idn^T) fused with clamp, diagonal masking,
// and full reduction. R7: fp8 e4m3 halves every memory-chain term (staging
// instrs, L2 fill, LDS write, LDS read) while MFMA rate is unchanged
// (fp8 16x16x32 = bf16 rate) -- R0..R6 showed the 67us plateau is the SUM
// of chain terms, so halve the chain, not the sync scheme.
// 2D grid: linear id = bi*64+bj, 64%8==0 => XCD = bj%8 -> per-XCD B-set
// (0.5 MB) L2-resident (R1 A/B: 31 vs 74 MB fetch). Upper-tri blocks only;
// strictly-upper tiles weighted 2x by symmetry.
__global__ __launch_bounds__(256) void sim_reduce_kernel(
    const unsigned char* __restrict__ idn, float* __restrict__ acc) {
  const int bi = blockIdx.y;
  const int bj = blockIdx.x;
  if (bj < bi) return;               // block-uniform early exit (dead block)

  __shared__ __align__(16) unsigned char As[BM * BK];   // 8 KB
  __shared__ __align__(16) unsigned char Bs[BM * BK];   // 8 KB

  const int tid  = threadIdx.x;      // 0..255, 4 waves
  const int lane = tid & 63;
  const int w    = tid >> 6;
  const int wr   = (w >> 1) * 64;    // wave's 64x64 quadrant
  const int wc   = (w & 1) * 64;
  const int q    = lane >> 4;        // 0..3
  const int r16  = lane & 15;
  const int m3   = r16 & 3;          // row's swizzle key (tile base % 4 == 0)
  const int h8   = (q & 1) * 8;      // 8B half within the 16B chunk
  // s=0 chunk: q>>1; s=1 chunk: 2+(q>>1) = (q>>1)^2. Swizzled positions:
  const int w0 = ((q >> 1) ^ m3);          // LDS 16B-position for k-step 0
  const int w1 = w0 ^ 2;                   // and for k-step 1

  f32x4 acc_f[4][4];
  #pragma unroll
  for (int i = 0; i < 4; i++)
    #pragma unroll
    for (int j = 0; j < 4; j++)
      acc_f[i][j] = (f32x4){0.f, 0.f, 0.f, 0.f};

  // Staging: 512 chunks of 16B per 128x64B tile; thread t covers chunks
  // t, t+256. Chunk c = row c>>2, window-pos c&3 -- addresses lane-linear
  // (4 lanes x 16B consecutive per row = fully coalesced 64B lines); memory
  // already holds the swizzled chunk order.
  const int c0 = tid, c1 = tid + 256;
  const unsigned char* gA0 = idn + (size_t)(bi * BM + (c0 >> 2)) * KDIM + (c0 & 3) * 16;
  const unsigned char* gA1 = idn + (size_t)(bi * BM + (c1 >> 2)) * KDIM + (c1 & 3) * 16;
  const unsigned char* gB0 = idn + (size_t)(bj * BM + (c0 >> 2)) * KDIM + (c0 & 3) * 16;
  const unsigned char* gB1 = idn + (size_t)(bj * BM + (c1 >> 2)) * KDIM + (c1 & 3) * 16;
  unsigned char* lA0 = As + c0 * 16;
  unsigned char* lA1 = As + c1 * 16;
  unsigned char* lB0 = Bs + c0 * 16;
  unsigned char* lB1 = Bs + c1 * 16;

  for (int t = 0; t < NKT; ++t) {
    const int ko = t * BK;
    async_copy16(gA0 + ko, lA0);
    async_copy16(gA1 + ko, lA1);
    async_copy16(gB0 + ko, lB0);
    async_copy16(gB1 + ko, lB1);
    asm volatile("s_waitcnt vmcnt(0)" ::: "memory");
    __syncthreads();

    // Fragments: lane (r16,q) for k-step s needs row-local bytes
    // [s*32 + q*8, +8) = global chunk 2s+(q>>1), half q&1 -> swizzled
    // position w_s. ds_read_b64; bank slots (row&1, pos, half) hold exactly
    // 4 lanes each -- minimal wrap count for b64.
    i64 a[2][4], b[2][4];
    #pragma unroll
    for (int mi = 0; mi < 4; mi++) {
      const int ra = (mi * 16 + r16) * BK;
      a[0][mi] = *(const i64*)&As[ra + w0 * 16 + h8];
      a[1][mi] = *(const i64*)&As[ra + w1 * 16 + h8];
      b[0][mi] = *(const i64*)&Bs[ra + w0 * 16 + h8];
      b[1][mi] = *(const i64*)&Bs[ra + w1 * 16 + h8];
    }
    #pragma unroll
    for (int s = 0; s < 2; s++)
      #pragma unroll
      for (int mi = 0; mi < 4; mi++)
        #pragma unroll
        for (int ni = 0; ni < 4; ni++)
          acc_f[mi][ni] = __builtin_amdgcn_mfma_f32_16x16x32_fp8_fp8(
              a[s][mi], b[s][ni], acc_f[mi][ni], 0, 0, 0);
    __syncthreads();
  }

  // Epilogue: clamp at zero, mask diagonal, reduce.
  // C/D layout (verified m89/m91; dtype-independent m121/m127/m128):
  // col = lane&15, row = (lane>>4)*4 + reg.
  float local = 0.f;
  const bool diag = (bi == bj);
  #pragma unroll
  for (int mi = 0; mi < 4; mi++)
    #pragma unroll
    for (int ni = 0; ni < 4; ni++)
      #pragma unroll
      for (int rr = 0; rr < 4; rr++) {
        const int ri = wr + mi * 16 + q * 4 + rr;
        const int ci = wc + ni * 16 + r16;
        float v = fmaxf(acc_f[mi][ni][rr], 0.f);
        if (diag && ri == ci) v = 0.f;
        local += v;
      }

  #pragma unroll
  for (int off = 32; off > 0; off >>= 1) local += __shfl_down(local, off);
  __syncthreads();                   // staging dead; reuse As for reduce
  float* red = (float*)As;
  if (lane == 0) red[w] = local;
  __syncthreads();
  if (tid == 0) {
    float s = red[0] + red[1] + red[2] + red[3];
    if (!diag) s *= 2.f;             // strictly-upper tiles cover both triangles
    atomicAdd(acc, s);
  }
}

// Kernel 3: scale and write both outputs (total_loss == l_id_div, DIV_COEF=1).
__global__ void finalize_kernel(const float* __restrict__ acc, float* __restrict__ out) {
  const float m = *acc * (1.0f / ((float)NROWS * (float)NROWS));
  out[0] = m;
  out[1] = m;
}

extern "C" void kernel_launch(void* const* d_in, const int* in_sizes, int n_in,
                              void* d_out, int out_size, void* d_ws, size_t ws_size,
                              hipStream_t stream) {
  const float* id = (const float*)d_in[0];
  float* out = (float*)d_out;
  unsigned char* idn = (unsigned char*)d_ws;                       // 4 MB fp8
  float* acc = (float*)((char*)d_ws + (size_t)NROWS * KDIM);

  prep_kernel<<<NROWS, 128, 0, stream>>>(id, idn, acc);
  dim3 grid(NT, NT);
  sim_reduce_kernel<<<grid, 256, 0, stream>>>(idn, acc);
  finalize_kernel<<<1, 1, 0, stream>>>(acc, out);
}

// Round 9
// 103.689 us; speedup vs baseline: 2.3075x; 1.1764x over previous
//
#include <hip/hip_runtime.h>
#include <stdint.h>

#define NROWS 8192
#define KDIM  512                           // k elems (= bytes in fp8) per row
#define BM    128
#define BK    256                           // k-bytes staged per iter (R8)
#define NKI   (KDIM / BK)                   // 2 K-iters
#define NT    (NROWS / BM)                  // 64 tiles per dim
#define NBLK  (NT * (NT + 1) / 2)           // 2080 upper-tri blocks

typedef __attribute__((ext_vector_type(4))) float f32x4;
typedef long i64;

__device__ __forceinline__ void async_copy16(const unsigned char* g, unsigned char* l) {
  __builtin_amdgcn_global_load_lds(
      (const __attribute__((address_space(1))) unsigned int*)g,
      (__attribute__((address_space(3))) unsigned int*)l,
      16, 0, 0);
}

// Kernel 1: row-normalize fp32 -> fp8 e4m3 (RNE via v_cvt_pk_fp8_f32),
// PRE-SWIZZLED layout: within each 256B window of a row, the 16B chunk
// holding global chunk g sits at position g ^ (row & 15). Sim kernel stages
// lane-linearly (coalesced, R2 lesson) and ds_read_b64 fragment reads land
// 2-way-wrapped (free, m136) instead of 16-way same-bank.
__global__ __launch_bounds__(128) void prep_kernel(
    const float* __restrict__ src, unsigned char* __restrict__ dst,
    float* __restrict__ acc) {
  const int row = blockIdx.x;
  const int tid = threadIdx.x;             // 128 thr x 4 elems
  const float4 v = ((const float4*)src)[row * 128 + tid];
  float ss = v.x * v.x + v.y * v.y + v.z * v.z + v.w * v.w;
  #pragma unroll
  for (int off = 32; off > 0; off >>= 1) ss += __shfl_down(ss, off);
  __shared__ float red[2];
  __shared__ float s_rn;
  const int lane = tid & 63, w = tid >> 6;
  if (lane == 0) red[w] = ss;
  __syncthreads();
  if (tid == 0) {
    s_rn = 1.0f / sqrtf(red[0] + red[1]);  // norms ~22.6, EPS can never fire
    if (row == 0) *acc = 0.0f;
  }
  __syncthreads();
  const float rn = s_rn;
  int pk = __builtin_amdgcn_cvt_pk_fp8_f32(v.x * rn, v.y * rn, 0, false);
  pk     = __builtin_amdgcn_cvt_pk_fp8_f32(v.z * rn, v.w * rn, pk, true);
  // this thread's 4B live in 16B chunk cg = tid>>2; window = cg>>4 (256B),
  // in-window index gin = cg&15 relocates to gin ^ (row&15).
  const int cg  = tid >> 2;
  const int win = cg >> 4;
  const int p   = (cg & 15) ^ (row & 15);
  ((unsigned int*)dst)[row * 128 + win * 64 + p * 4 + (tid & 3)] = (unsigned int)pk;
}

__device__ __forceinline__ int tri_base(int b) {   // # tiles before row b
  return b * NT - (b * (b - 1)) / 2;
}

// Kernel 2: fp8 MFMA GEMM (idn @ idn^T) fused with clamp, diagonal masking,
// full reduction. R8: BK=256 -> only 2 K-iters. R0-R7 showed the plateau is
// per-iter latency exposure (issue -> vmcnt(0) L2 roundtrip -> barrier ->
// dep-chained compute) x iter count: every >=8-iter variant sat at 61-80us
// while all pipes ran <31%. 64KB LDS (2 blocks/CU), 128 MFMA per fill.
// 1D triangular grid (no dead blocks): safe now -- whole 4MB fp8 matrix is
// L2-resident per XCD (R7 hbm_bytes ~ 66KB), so R1's locality regression
// cannot recur. Strictly-upper tiles weighted 2x by symmetry.
__global__ __launch_bounds__(256) void sim_reduce_kernel(
    const unsigned char* __restrict__ idn, float* __restrict__ acc) {
  // triangular decode (block-uniform scalar math, R1-proven)
  const int idx = blockIdx.x;
  const float Af = 2.0f * NT + 1.0f;
  int bi = (int)((Af - sqrtf(Af * Af - 8.0f * (float)idx)) * 0.5f);
  while (bi > 0 && tri_base(bi) > idx) bi--;
  while (tri_base(bi + 1) <= idx) bi++;
  const int bj = bi + (idx - tri_base(bi));

  __shared__ __align__(16) unsigned char As[BM * BK];   // 32 KB
  __shared__ __align__(16) unsigned char Bs[BM * BK];   // 32 KB

  const int tid  = threadIdx.x;      // 0..255, 4 waves
  const int lane = tid & 63;
  const int w    = tid >> 6;
  const int wr   = (w >> 1) * 64;    // wave's 64x64 quadrant
  const int wc   = (w & 1) * 64;
  const int q    = lane >> 4;        // 0..3
  const int r16  = lane & 15;
  const int h8   = (q & 1) * 8;      // 8B half within a 16B chunk

  f32x4 acc_f[4][4];
  #pragma unroll
  for (int i = 0; i < 4; i++)
    #pragma unroll
    for (int j = 0; j < 4; j++)
      acc_f[i][j] = (f32x4){0.f, 0.f, 0.f, 0.f};

  // Staging: 2048 chunks of 16B per 128x256B tile; thread t covers chunks
  // t + i*256 (i=0..7) -> row (tid>>4)+i*16, in-window pos tid&15.
  // Lane-linear LDS dest (wave-uniform base + lane*16); 16 lanes cover a
  // full 256B row -> fully coalesced. Memory already holds swizzled order.
  const unsigned char* gA = idn + (size_t)(bi * BM + (tid >> 4)) * KDIM + (tid & 15) * 16;
  const unsigned char* gB = idn + (size_t)(bj * BM + (tid >> 4)) * KDIM + (tid & 15) * 16;
  unsigned char* lA = As + tid * 16;
  unsigned char* lB = Bs + tid * 16;

  #pragma unroll
  for (int t = 0; t < NKI; ++t) {
    if (t) __syncthreads();          // WAR: prior tile fully consumed
    const int ko = t * BK;
    #pragma unroll
    for (int i = 0; i < 8; i++) async_copy16(gA + ko + i * 8192, lA + i * 4096);
    #pragma unroll
    for (int i = 0; i < 8; i++) async_copy16(gB + ko + i * 8192, lB + i * 4096);
    asm volatile("s_waitcnt vmcnt(0)" ::: "memory");
    __syncthreads();

    // 8 k-steps per fill. Lane (r16,q), k-step s needs row-local bytes
    // [s*32+q*8, +8): chunk 2s+(q>>1), half q&1, at swizzled pos ^ r16.
    // Banks: pos*4 mod 32 over 16 distinct pos -> 2 lanes/bank (free).
    #pragma unroll
    for (int s = 0; s < 8; s++) {
      const int pos = ((2 * s + (q >> 1)) ^ r16) * 16 + h8;
      i64 a[4], b[4];
      #pragma unroll
      for (int mi = 0; mi < 4; mi++) {
        a[mi] = *(const i64*)&As[(wr + mi * 16 + r16) * BK + pos];
        b[mi] = *(const i64*)&Bs[(wc + mi * 16 + r16) * BK + pos];
      }
      #pragma unroll
      for (int mi = 0; mi < 4; mi++)
        #pragma unroll
        for (int ni = 0; ni < 4; ni++)
          acc_f[mi][ni] = __builtin_amdgcn_mfma_f32_16x16x32_fp8_fp8(
              a[mi], b[ni], acc_f[mi][ni], 0, 0, 0);
    }
  }

  // Epilogue: clamp at zero, mask diagonal, reduce.
  // C/D layout (verified m89/m91; dtype-independent m121/m127/m128):
  // col = lane&15, row = (lane>>4)*4 + reg.
  float local = 0.f;
  const bool diag = (bi == bj);
  #pragma unroll
  for (int mi = 0; mi < 4; mi++)
    #pragma unroll
    for (int ni = 0; ni < 4; ni++)
      #pragma unroll
      for (int rr = 0; rr < 4; rr++) {
        const int ri = wr + mi * 16 + q * 4 + rr;
        const int ci = wc + ni * 16 + r16;
        float v = fmaxf(acc_f[mi][ni][rr], 0.f);
        if (diag && ri == ci) v = 0.f;
        local += v;
      }

  #pragma unroll
  for (int off = 32; off > 0; off >>= 1) local += __shfl_down(local, off);
  __syncthreads();                   // staging dead; reuse As for reduce
  float* red = (float*)As;
  if (lane == 0) red[w] = local;
  __syncthreads();
  if (tid == 0) {
    float s = red[0] + red[1] + red[2] + red[3];
    if (!diag) s *= 2.f;             // strictly-upper tiles cover both triangles
    atomicAdd(acc, s);
  }
}

// Kernel 3: scale and write both outputs (total_loss == l_id_div, DIV_COEF=1).
__global__ void finalize_kernel(const float* __restrict__ acc, float* __restrict__ out) {
  const float m = *acc * (1.0f / ((float)NROWS * (float)NROWS));
  out[0] = m;
  out[1] = m;
}

extern "C" void kernel_launch(void* const* d_in, const int* in_sizes, int n_in,
                              void* d_out, int out_size, void* d_ws, size_t ws_size,
                              hipStream_t stream) {
  const float* id = (const float*)d_in[0];
  float* out = (float*)d_out;
  unsigned char* idn = (unsigned char*)d_ws;                       // 4 MB fp8
  float* acc = (float*)((char*)d_ws + (size_t)NROWS * KDIM);

  prep_kernel<<<NROWS, 128, 0, stream>>>(id, idn, acc);
  sim_reduce_kernel<<<NBLK, 256, 0, stream>>>(idn, acc);
  finalize_kernel<<<1, 1, 0, stream>>>(acc, out);
}

// Round 10
// 100.466 us; speedup vs baseline: 2.3815x; 1.0321x over previous
//
#include <hip/hip_runtime.h>
#include <stdint.h>

#define NROWS 8192
#define KDIM  512                           // k elems (= bytes in fp8) per row
#define BM    128
#define BK    256                           // k-bytes staged per iter
#define NKI   (KDIM / BK)                   // 2 K-iters
#define NT    (NROWS / BM)                  // 64 tiles per dim
#define NBLK  (NT * (NT + 1) / 2)           // 2080 upper-tri blocks

typedef __attribute__((ext_vector_type(4))) float f32x4;
typedef long i64;

__device__ __forceinline__ void async_copy16(const unsigned char* g, unsigned char* l) {
  __builtin_amdgcn_global_load_lds(
      (const __attribute__((address_space(1))) unsigned int*)g,
      (__attribute__((address_space(3))) unsigned int*)l,
      16, 0, 0);
}

// Kernel 1: row-normalize fp32 -> fp8 e4m3 (RNE), one wave per row (no LDS,
// no barriers). PRE-SWIZZLED layout, two levels:
//   (a) 16B chunk g of each 256B window sits at position g ^ (row & 15)
//       (R3/R8 technique: sim stages lane-linearly = coalesced).
//   (b) NEW (R9): the two 8B halves inside each chunk are swapped iff
//       bit 3 of row is set. R8 post-mortem: with a 256B LDS row stride the
//       row contributes nothing to the bank and chunk*4 mod 32 loses chunk
//       bit 3, so each 16-lane phase covered only 16/32 banks -> 4 extra
//       cyc per ds_read_b64 (4.26M conflict cycles). The half-swap re-keys
//       the lost bit into the 8B-half select: each phase now hits all 16
//       even bank-starts exactly once -> all 32 banks, zero conflicts.
__global__ __launch_bounds__(256) void prep_kernel(
    const float* __restrict__ src, unsigned char* __restrict__ dst,
    float* __restrict__ acc) {
  const int row  = blockIdx.x * 4 + (threadIdx.x >> 6);
  const int lane = threadIdx.x & 63;
  const float4 v0 = ((const float4*)src)[row * 128 + lane * 2];
  const float4 v1 = ((const float4*)src)[row * 128 + lane * 2 + 1];
  float ss = v0.x * v0.x + v0.y * v0.y + v0.z * v0.z + v0.w * v0.w
           + v1.x * v1.x + v1.y * v1.y + v1.z * v1.z + v1.w * v1.w;
  #pragma unroll
  for (int off = 32; off > 0; off >>= 1) ss += __shfl_down(ss, off);
  const float rn = 1.0f / sqrtf(__shfl(ss, 0));   // norms ~22.6, EPS never fires
  if (row == 0 && lane == 0) *acc = 0.0f;
  int pk0 = __builtin_amdgcn_cvt_pk_fp8_f32(v0.x * rn, v0.y * rn, 0, false);
  pk0     = __builtin_amdgcn_cvt_pk_fp8_f32(v0.z * rn, v0.w * rn, pk0, true);
  int pk1 = __builtin_amdgcn_cvt_pk_fp8_f32(v1.x * rn, v1.y * rn, 0, false);
  pk1     = __builtin_amdgcn_cvt_pk_fp8_f32(v1.z * rn, v1.w * rn, pk1, true);
  // lane's 8 logical bytes = chunk cg = lane>>1 (win = cg>>4), half = lane&1.
  const int cg = lane >> 1;
  const int win = cg >> 4;
  const int p  = (cg & 15) ^ (row & 15);           // swizzle (a)
  const int hf = (lane & 1) ^ ((row >> 3) & 1);    // swizzle (b)
  uint2 o; o.x = (unsigned int)pk0; o.y = (unsigned int)pk1;
  ((uint2*)dst)[row * 64 + win * 32 + p * 2 + hf] = o;
}

__device__ __forceinline__ int tri_base(int b) {   // # tiles before row b
  return b * NT - (b * (b - 1)) / 2;
}

// Kernel 2: fp8 MFMA GEMM (idn @ idn^T) fused with clamp, diagonal masking,
// full reduction. BK=256 -> 2 K-iters (R8: latency-exposure x iter-count is
// the plateau; 8->2 iters bought 61->48.5us). 64KB LDS, 128 MFMA per fill.
// 1D triangular grid -- whole 4MB fp8 matrix is L2-resident per XCD
// (R7/R8 hbm_bytes ~ 66KB/17MB), so R1's locality regression cannot recur.
// Strictly-upper tiles weighted 2x by symmetry.
__global__ __launch_bounds__(256) void sim_reduce_kernel(
    const unsigned char* __restrict__ idn, float* __restrict__ acc) {
  // triangular decode (block-uniform scalar math, R1-proven)
  const int idx = blockIdx.x;
  const float Af = 2.0f * NT + 1.0f;
  int bi = (int)((Af - sqrtf(Af * Af - 8.0f * (float)idx)) * 0.5f);
  while (bi > 0 && tri_base(bi) > idx) bi--;
  while (tri_base(bi + 1) <= idx) bi++;
  const int bj = bi + (idx - tri_base(bi));

  __shared__ __align__(16) unsigned char As[BM * BK];   // 32 KB
  __shared__ __align__(16) unsigned char Bs[BM * BK];   // 32 KB

  const int tid  = threadIdx.x;      // 0..255, 4 waves
  const int lane = tid & 63;
  const int w    = tid >> 6;
  const int wr   = (w >> 1) * 64;    // wave's 64x64 quadrant
  const int wc   = (w & 1) * 64;
  const int q    = lane >> 4;        // 0..3
  const int r16  = lane & 15;
  // R9: physical 8B half = logical half (q&1) XOR row bit 3 (prep half-swap)
  const int hq   = (((q & 1) ^ ((r16 >> 3) & 1))) * 8;

  f32x4 acc_f[4][4];
  #pragma unroll
  for (int i = 0; i < 4; i++)
    #pragma unroll
    for (int j = 0; j < 4; j++)
      acc_f[i][j] = (f32x4){0.f, 0.f, 0.f, 0.f};

  // Staging: 2048 chunks of 16B per 128x256B tile; thread t covers row
  // (t>>4)+i*16 (i=0..7), in-window pos t&15. Lane-linear LDS dest
  // (wave-uniform base + lane*16); 16 lanes cover a full 256B row ->
  // fully coalesced. Memory already holds the swizzled chunk order.
  const unsigned char* gA = idn + (size_t)(bi * BM + (tid >> 4)) * KDIM + (tid & 15) * 16;
  const unsigned char* gB = idn + (size_t)(bj * BM + (tid >> 4)) * KDIM + (tid & 15) * 16;
  unsigned char* lA = As + tid * 16;
  unsigned char* lB = Bs + tid * 16;

  #pragma unroll
  for (int t = 0; t < NKI; ++t) {
    if (t) __syncthreads();          // WAR: prior tile fully consumed
    const int ko = t * BK;
    #pragma unroll
    for (int i = 0; i < 8; i++) async_copy16(gA + ko + i * 8192, lA + i * 4096);
    #pragma unroll
    for (int i = 0; i < 8; i++) async_copy16(gB + ko + i * 8192, lB + i * 4096);
    asm volatile("s_waitcnt vmcnt(0)" ::: "memory");
    __syncthreads();

    // 8 k-steps per fill. Lane (r16,q), k-step s: logical chunk 2s+(q>>1)
    // at swizzled pos ^ r16, physical half hq. Per 16-lane phase the
    // bank-starts are all 16 even values -> all 32 banks once (optimal).
    #pragma unroll
    for (int s = 0; s < 8; s++) {
      const int pos = ((2 * s + (q >> 1)) ^ r16) * 16 + hq;
      i64 a[4], b[4];
      #pragma unroll
      for (int mi = 0; mi < 4; mi++) {
        a[mi] = *(const i64*)&As[(wr + mi * 16 + r16) * BK + pos];
        b[mi] = *(const i64*)&Bs[(wc + mi * 16 + r16) * BK + pos];
      }
      #pragma unroll
      for (int mi = 0; mi < 4; mi++)
        #pragma unroll
        for (int ni = 0; ni < 4; ni++)
          acc_f[mi][ni] = __builtin_amdgcn_mfma_f32_16x16x32_fp8_fp8(
              a[mi], b[ni], acc_f[mi][ni], 0, 0, 0);
    }
  }

  // Epilogue: clamp at zero, mask diagonal, reduce.
  // C/D layout (verified m89/m91; dtype-independent m121/m127/m128):
  // col = lane&15, row = (lane>>4)*4 + reg.
  float local = 0.f;
  const bool diag = (bi == bj);
  #pragma unroll
  for (int mi = 0; mi < 4; mi++)
    #pragma unroll
    for (int ni = 0; ni < 4; ni++)
      #pragma unroll
      for (int rr = 0; rr < 4; rr++) {
        const int ri = wr + mi * 16 + q * 4 + rr;
        const int ci = wc + ni * 16 + r16;
        float v = fmaxf(acc_f[mi][ni][rr], 0.f);
        if (diag && ri == ci) v = 0.f;
        local += v;
      }

  #pragma unroll
  for (int off = 32; off > 0; off >>= 1) local += __shfl_down(local, off);
  __syncthreads();                   // staging dead; reuse As for reduce
  float* red = (float*)As;
  if (lane == 0) red[w] = local;
  __syncthreads();
  if (tid == 0) {
    float s = red[0] + red[1] + red[2] + red[3];
    if (!diag) s *= 2.f;             // strictly-upper tiles cover both triangles
    atomicAdd(acc, s);
  }
}

// Kernel 3: scale and write both outputs (total_loss == l_id_div, DIV_COEF=1).
__global__ void finalize_kernel(const float* __restrict__ acc, float* __restrict__ out) {
  const float m = *acc * (1.0f / ((float)NROWS * (float)NROWS));
  out[0] = m;
  out[1] = m;
}

extern "C" void kernel_launch(void* const* d_in, const int* in_sizes, int n_in,
                              void* d_out, int out_size, void* d_ws, size_t ws_size,
                              hipStream_t stream) {
  const float* id = (const float*)d_in[0];
  float* out = (float*)d_out;
  unsigned char* idn = (unsigned char*)d_ws;                       // 4 MB fp8
  float* acc = (float*)((char*)d_ws + (size_t)NROWS * KDIM);

  prep_kernel<<<NROWS / 4, 256, 0, stream>>>(id, idn, acc);
  sim_reduce_kernel<<<NBLK, 256, 0, stream>>>(idn, acc);
  finalize_kernel<<<1, 1, 0, stream>>>(acc, out);
}

// Round 12
// 98.127 us; speedup vs baseline: 2.4383x; 1.0238x over previous
//
#include <hip/hip_runtime.h>
#include <stdint.h>

#define NROWS 8192
#define KDIM  512                           // k elems (= bytes in fp8) per row
#define BM    128
#define BK    128                           // k-bytes per stage
#define NKI   (KDIM / BK)                   // 4 K-iters
#define NT    (NROWS / BM)                  // 64 tiles per dim
#define NBLK  (NT * (NT + 1) / 2)           // 2080 upper-tri blocks

typedef __attribute__((ext_vector_type(4))) float f32x4;
typedef long i64;

__device__ __forceinline__ void async_copy16(const unsigned char* g, unsigned char* l) {
  __builtin_amdgcn_global_load_lds(
      (const __attribute__((address_space(1))) unsigned int*)g,
      (__attribute__((address_space(3))) unsigned int*)l,
      16, 0, 0);
}

// Kernel 1: row-normalize fp32 -> fp8 e4m3 (RNE), one wave per row (no LDS,
// no barriers). PRE-SWIZZLED layout for BK=128 staging windows:
//   (a) within each 128B window, 16B chunk c sits at position c ^ (row & 7)
//   (b) the two 8B halves inside each chunk are swapped iff row bit 3 is set
// With a 128B LDS row stride only chunk-pos + half select the bank; (a)+(b)
// make each 16-lane read phase hit all 16 even bank-starts once -> all 32
// banks, zero conflicts (R9 measured 4.26M -> 0 with this scheme).
// R10 BUG FIX (R11): window stride is 128B = 16 uint2 -- the win*8 store
// index made windows overlap (win=1,p=0 == win=0,p=4), scrambling half the
// matrix (absmax 15.6). Now win*16.
__global__ __launch_bounds__(256) void prep_kernel(
    const float* __restrict__ src, unsigned char* __restrict__ dst,
    float* __restrict__ acc) {
  const int row  = blockIdx.x * 4 + (threadIdx.x >> 6);
  const int lane = threadIdx.x & 63;
  const float4 v0 = ((const float4*)src)[row * 128 + lane * 2];
  const float4 v1 = ((const float4*)src)[row * 128 + lane * 2 + 1];
  float ss = v0.x * v0.x + v0.y * v0.y + v0.z * v0.z + v0.w * v0.w
           + v1.x * v1.x + v1.y * v1.y + v1.z * v1.z + v1.w * v1.w;
  #pragma unroll
  for (int off = 32; off > 0; off >>= 1) ss += __shfl_down(ss, off);
  const float rn = 1.0f / sqrtf(__shfl(ss, 0));   // norms ~22.6, EPS never fires
  if (row == 0 && lane == 0) *acc = 0.0f;
  int pk0 = __builtin_amdgcn_cvt_pk_fp8_f32(v0.x * rn, v0.y * rn, 0, false);
  pk0     = __builtin_amdgcn_cvt_pk_fp8_f32(v0.z * rn, v0.w * rn, pk0, true);
  int pk1 = __builtin_amdgcn_cvt_pk_fp8_f32(v1.x * rn, v1.y * rn, 0, false);
  pk1     = __builtin_amdgcn_cvt_pk_fp8_f32(v1.z * rn, v1.w * rn, pk1, true);
  // lane's 8 logical bytes = 16B chunk cg = lane>>1, half = lane&1.
  const int cg  = lane >> 1;
  const int win = cg >> 3;                          // 128B window (0..3)
  const int p   = (cg & 7) ^ (row & 7);             // swizzle (a)
  const int hf  = (lane & 1) ^ ((row >> 3) & 1);    // swizzle (b)
  uint2 o; o.x = (unsigned int)pk0; o.y = (unsigned int)pk1;
  ((uint2*)dst)[row * 64 + win * 16 + p * 2 + hf] = o;   // R11 fix: win*16
}

__device__ __forceinline__ int tri_base(int b) {   // # tiles before row b
  return b * NT - (b * (b - 1)) / 2;
}

// Kernel 2: fp8 MFMA GEMM (idn @ idn^T) fused with clamp, diagonal masking,
// full reduction.
// 2-stage double-buffered K-loop, BK=128, 4 iters. R9 post-mortem: per-CU
// floors are MFMA 16.8us, L2->LDS transfer ~17us, LDS ~10us; measured 46.6us
// ~ their SUM -- the vmcnt(0)+barrier convoy serialized transfer vs compute.
// Here stage t+1's 8 loads/thread stay in flight across compute of stage t
// (s_waitcnt vmcnt(8), never 0 until the last iter) -- AITER-style pipeline.
// WAR ordering: tail barrier of iter t orders all waves' compute(t) before
// iter t+1's prefetch-issue into the just-consumed stage.
// 1D triangular grid -- whole 4MB fp8 matrix is L2-resident per XCD.
// Strictly-upper tiles weighted 2x by symmetry.
__global__ __launch_bounds__(256) void sim_reduce_kernel(
    const unsigned char* __restrict__ idn, float* __restrict__ acc) {
  // triangular decode (block-uniform scalar math, R1-proven)
  const int idx = blockIdx.x;
  const float Af = 2.0f * NT + 1.0f;
  int bi = (int)((Af - sqrtf(Af * Af - 8.0f * (float)idx)) * 0.5f);
  while (bi > 0 && tri_base(bi) > idx) bi--;
  while (tri_base(bi + 1) <= idx) bi++;
  const int bj = bi + (idx - tri_base(bi));

  __shared__ __align__(16) unsigned char As[2][BM * BK];   // 2 x 16 KB
  __shared__ __align__(16) unsigned char Bs[2][BM * BK];   // 2 x 16 KB

  const int tid  = threadIdx.x;      // 0..255, 4 waves
  const int lane = tid & 63;
  const int w    = tid >> 6;
  const int wr   = (w >> 1) * 64;    // wave's 64x64 quadrant
  const int wc   = (w & 1) * 64;
  const int q    = lane >> 4;        // 0..3
  const int r16  = lane & 15;
  const int rx   = r16 & 7;          // swizzle key (a)
  const int hq   = ((q & 1) ^ ((r16 >> 3) & 1)) * 8;   // physical half (b)

  f32x4 acc_f[4][4];
  #pragma unroll
  for (int i = 0; i < 4; i++)
    #pragma unroll
    for (int j = 0; j < 4; j++)
      acc_f[i][j] = (f32x4){0.f, 0.f, 0.f, 0.f};

  // Staging: per stage, 1024 chunks of 16B; thread t covers chunks t+i*256
  // (i=0..3): row (t>>3)+i*32, in-window pos t&7. 8 lanes cover one row's
  // 128B window contiguously -> coalesced. Memory already holds the
  // swizzled chunk order; LDS dest lane-linear (c*16).
  const unsigned char* gA = idn + (size_t)(bi * BM + (tid >> 3)) * KDIM + (tid & 7) * 16;
  const unsigned char* gB = idn + (size_t)(bj * BM + (tid >> 3)) * KDIM + (tid & 7) * 16;
  const int ldso = tid * 16;         // + i*4096 per chunk group

  // prologue: stage 0 <- k-window 0
  #pragma unroll
  for (int i = 0; i < 4; i++) async_copy16(gA + (size_t)i * 16384, &As[0][ldso + i * 4096]);
  #pragma unroll
  for (int i = 0; i < 4; i++) async_copy16(gB + (size_t)i * 16384, &Bs[0][ldso + i * 4096]);

  #pragma unroll
  for (int t = 0; t < NKI; ++t) {
    const int cs = t & 1;
    if (t + 1 < NKI) {
      const int ns = cs ^ 1;
      const int ko = (t + 1) * BK;
      #pragma unroll
      for (int i = 0; i < 4; i++)
        async_copy16(gA + ko + (size_t)i * 16384, &As[ns][ldso + i * 4096]);
      #pragma unroll
      for (int i = 0; i < 4; i++)
        async_copy16(gB + ko + (size_t)i * 16384, &Bs[ns][ldso + i * 4096]);
      asm volatile("s_waitcnt vmcnt(8)" ::: "memory");  // stage t landed; t+1 in flight
    } else {
      asm volatile("s_waitcnt vmcnt(0)" ::: "memory");
    }
    asm volatile("s_barrier" ::: "memory");   // all waves' stage-t fills visible

    // 4 k-steps per stage. Lane (r16,q), k-step s: logical chunk 2s+(q>>1)
    // at swizzled pos ^ rx, physical half hq. Conflict-free (see prep).
    #pragma unroll
    for (int s = 0; s < 4; s++) {
      const int pos = ((2 * s + (q >> 1)) ^ rx) * 16 + hq;
      i64 a[4], b[4];
      #pragma unroll
      for (int mi = 0; mi < 4; mi++) {
        a[mi] = *(const i64*)&As[cs][(wr + mi * 16 + r16) * BK + pos];
        b[mi] = *(const i64*)&Bs[cs][(wc + mi * 16 + r16) * BK + pos];
      }
      #pragma unroll
      for (int mi = 0; mi < 4; mi++)
        #pragma unroll
        for (int ni = 0; ni < 4; ni++)
          acc_f[mi][ni] = __builtin_amdgcn_mfma_f32_16x16x32_fp8_fp8(
              a[mi], b[ni], acc_f[mi][ni], 0, 0, 0);
    }

    asm volatile("s_barrier" ::: "memory");   // compute(t) done before t+1 refill
  }

  // Epilogue: clamp at zero, mask diagonal, reduce.
  // C/D layout (verified m89/m91; dtype-independent m121/m127/m128):
  // col = lane&15, row = (lane>>4)*4 + reg.
  float local = 0.f;
  const bool diag = (bi == bj);
  #pragma unroll
  for (int mi = 0; mi < 4; mi++)
    #pragma unroll
    for (int ni = 0; ni < 4; ni++)
      #pragma unroll
      for (int rr = 0; rr < 4; rr++) {
        const int ri = wr + mi * 16 + q * 4 + rr;
        const int ci = wc + ni * 16 + r16;
        float v = fmaxf(acc_f[mi][ni][rr], 0.f);
        if (diag && ri == ci) v = 0.f;
        local += v;
      }

  #pragma unroll
  for (int off = 32; off > 0; off >>= 1) local += __shfl_down(local, off);
  __syncthreads();                   // staging dead; reuse As for reduce
  float* red = (float*)As;
  if (lane == 0) red[w] = local;
  __syncthreads();
  if (tid == 0) {
    float s = red[0] + red[1] + red[2] + red[3];
    if (!diag) s *= 2.f;             // strictly-upper tiles cover both triangles
    atomicAdd(acc, s);
  }
}

// Kernel 3: scale and write both outputs (total_loss == l_id_div, DIV_COEF=1).
__global__ void finalize_kernel(const float* __restrict__ acc, float* __restrict__ out) {
  const float m = *acc * (1.0f / ((float)NROWS * (float)NROWS));
  out[0] = m;
  out[1] = m;
}

extern "C" void kernel_launch(void* const* d_in, const int* in_sizes, int n_in,
                              void* d_out, int out_size, void* d_ws, size_t ws_size,
                              hipStream_t stream) {
  const float* id = (const float*)d_in[0];
  float* out = (float*)d_out;
  unsigned char* idn = (unsigned char*)d_ws;                       // 4 MB fp8
  float* acc = (float*)((char*)d_ws + (size_t)NROWS * KDIM);

  prep_kernel<<<NROWS / 4, 256, 0, stream>>>(id, idn, acc);
  sim_reduce_kernel<<<NBLK, 256, 0, stream>>>(idn, acc);
  finalize_kernel<<<1, 1, 0, stream>>>(acc, out);
}